// Round 3
// baseline (72.225 us; speedup 1.0000x reference)
//
#include <hip/hip_runtime.h>

// Fuzzy decoder: num[p,s,o] = max_k min(t0[s,k], t_p[k,o]); out = t + num - t*num.
// S=K=O=512, p in {0,1}. Semiring GEMM on packed fp16 (v_pk_min/v_pk_max), fp32 epilogue.

#define SDIM 512
#define TS 64     // s-tile per block
#define TO 32     // o-tile per block
#define BK 64     // k per chunk (32 packed k2)
#define BK2 32
#define NCH (SDIM / BK)   // 8 chunks
#define ASTR 36   // padded stride for Als[s][k2]

typedef _Float16 h2 __attribute__((ext_vector_type(2)));

__device__ __forceinline__ h2 pack2(float a, float b) {
    return __builtin_bit_cast(h2, __builtin_amdgcn_cvt_pkrtz(a, b));  // v_cvt_pkrtz_f16_f32
}
__device__ __forceinline__ h2 pmin(h2 a, h2 b) { return __builtin_elementwise_min(a, b); }
__device__ __forceinline__ h2 pmax(h2 a, h2 b) { return __builtin_elementwise_max(a, b); }

__global__ __launch_bounds__(256) void fuzzy_compose_kernel(
        const float* __restrict__ t, float* __restrict__ out) {
    // A tile: packed h2 of (k, k+1) per s:  Als[s][k2], pad 36 (reads are broadcast)
    __shared__ h2 Als[TS][ASTR];
    // B tile: packed h2 of rows (k, k+1) at col o: Bls[k2][o]
    __shared__ h2 Bls[BK2][TO];

    const int tid = threadIdx.x;
    const int o0 = blockIdx.x * TO;   // 16 o-tiles
    const int s0 = blockIdx.y * TS;   // 8 s-tiles
    const int p  = blockIdx.z;        // 2 predicates

    const float* __restrict__ A = t;                      // always t0
    const float* __restrict__ B = t + p * (SDIM * SDIM);  // t0 or t1

    // compute mapping: 4 s-rows x 2 o-cols per thread
    const int og = tid & 15, sg = tid >> 4;
    const int ol = og * 2, sl = sg * 4;

    // staging mapping A: row ar, col-quad aq (16 floats = 4 float4 along k)
    const int ar = tid >> 2, aq = tid & 3;
    // staging mapping B: k-pair bk, o-quad bq (float4 from rows 2bk, 2bk+1)
    const int bk = tid >> 3, bq = tid & 7;

    const float4* __restrict__ Arow =
        reinterpret_cast<const float4*>(A + (s0 + ar) * SDIM);

    h2 acc[4][2];
    #pragma unroll
    for (int j = 0; j < 4; ++j)
        #pragma unroll
        for (int i = 0; i < 2; ++i)
            acc[j][i] = pack2(0.f, 0.f);   // num >= 0, so 0 is max-identity

    float4 fa[4], fx, fy;
    // prologue: load chunk 0
    #pragma unroll
    for (int q4 = 0; q4 < 4; ++q4) fa[q4] = Arow[aq * 4 + q4];
    fx = *reinterpret_cast<const float4*>(B + (2 * bk) * SDIM + o0 + bq * 4);
    fy = *reinterpret_cast<const float4*>(B + (2 * bk + 1) * SDIM + o0 + bq * 4);

    for (int c = 0; c < NCH; ++c) {
        // staged regs -> LDS (prev compute finished at loop-tail barrier)
        #pragma unroll
        for (int q4 = 0; q4 < 4; ++q4) {
            Als[ar][aq * 8 + q4 * 2 + 0] = pack2(fa[q4].x, fa[q4].y);
            Als[ar][aq * 8 + q4 * 2 + 1] = pack2(fa[q4].z, fa[q4].w);
        }
        Bls[bk][bq * 4 + 0] = pack2(fx.x, fy.x);
        Bls[bk][bq * 4 + 1] = pack2(fx.y, fy.y);
        Bls[bk][bq * 4 + 2] = pack2(fx.z, fy.z);
        Bls[bk][bq * 4 + 3] = pack2(fx.w, fy.w);
        __syncthreads();

        // prefetch next chunk (overlaps with compute below)
        if (c + 1 < NCH) {
            const int k0 = (c + 1) * BK;
            #pragma unroll
            for (int q4 = 0; q4 < 4; ++q4) fa[q4] = Arow[k0 / 4 + aq * 4 + q4];
            fx = *reinterpret_cast<const float4*>(B + (k0 + 2 * bk) * SDIM + o0 + bq * 4);
            fy = *reinterpret_cast<const float4*>(B + (k0 + 2 * bk + 1) * SDIM + o0 + bq * 4);
        }

        // max-min inner loop: 16 pk-instrs per k2 per thread
        #pragma unroll
        for (int k2 = 0; k2 < BK2; ++k2) {
            const h2 b0 = Bls[k2][ol];
            const h2 b1 = Bls[k2][ol + 1];
            #pragma unroll
            for (int j = 0; j < 4; ++j) {
                const h2 a = Als[sl + j][k2];
                acc[j][0] = pmax(acc[j][0], pmin(a, b0));
                acc[j][1] = pmax(acc[j][1], pmin(a, b1));
            }
        }
        __syncthreads();
    }

    // fused epilogue: num = max(even-k acc, odd-k acc); out = t + num - t*num (fp32)
    const float* __restrict__ tp = t + p * (SDIM * SDIM);
    float* __restrict__ op = out + p * (SDIM * SDIM);
    #pragma unroll
    for (int j = 0; j < 4; ++j) {
        const int row = s0 + sl + j;
        const float2 tv = *reinterpret_cast<const float2*>(tp + row * SDIM + o0 + ol);
        const float n0 = fmaxf((float)acc[j][0][0], (float)acc[j][0][1]);
        const float n1 = fmaxf((float)acc[j][1][0], (float)acc[j][1][1]);
        float2 r;
        r.x = tv.x + n0 - tv.x * n0;
        r.y = tv.y + n1 - tv.y * n1;
        *reinterpret_cast<float2*>(op + row * SDIM + o0 + ol) = r;
    }
}

extern "C" void kernel_launch(void* const* d_in, const int* in_sizes, int n_in,
                              void* d_out, int out_size, void* d_ws, size_t ws_size,
                              hipStream_t stream) {
    const float* t = (const float*)d_in[0];
    float* out = (float*)d_out;
    dim3 grid(SDIM / TO, SDIM / TS, 2);   // 16 x 8 x 2 = 256 blocks
    fuzzy_compose_kernel<<<grid, 256, 0, stream>>>(t, out);
}